// Round 9
// baseline (385.641 us; speedup 1.0000x reference)
//
#include <hip/hip_runtime.h>
#include <hip/hip_bf16.h>

// Connected filter:
//   vals[i] = sigmoid(clamp(100*(attrs[i]·w + b), ±12)) * residue[i]
//   cum[i]  = sum of vals along parent chain from i up to root (dummy N terminates)
//   out[p]  = cum[pixel_to_node[p]]
// parent[i] < i (topological), parent[N] = N (dummy, val 0).
//
// Schedule (DAG-overlapped; fuse BW-bound with latency-bound, never BW+BW):
//   A: gate+pack | bin-count       B: walk L0 | scan
//   C: scatter | walk L1           D: walk L2
//   E: walk L3 | gather bins 0-1   (bins 0-1 = nodes < c2, cum ready after D;
//                                   walk3 BW-bound + gather latency-bound)
//   F: gather bins 2-7             G: merge
// Lessons baked in:
//  - nt-* builtins need ext_vector_type. nt-STORES double WRITE_SIZE -> never.
//  - >4 contiguous floats/thread leak partial-line writebacks -> x4 lane-dense.
//  - R8: fusing two BW-bound phases (scatter+walk3) = zero overlap (107us =
//    45+60, 3.5TB/s shared). Only mixed-pipe fusions pay.

typedef float v2f __attribute__((ext_vector_type(2)));
typedef float v4f __attribute__((ext_vector_type(4)));
typedef int   v4i __attribute__((ext_vector_type(4)));

// ---------------- A: fused gate+pack | bin-count ------------------------------
__global__ void k_gate_count(const float* __restrict__ attrs,
                             const float* __restrict__ w,
                             const float* __restrict__ bias,
                             const float* __restrict__ residue,
                             const int*   __restrict__ parent,
                             int2* __restrict__ packed, int N,
                             const int* __restrict__ ptn,
                             int* __restrict__ counts, int shift, int g1) {
    if ((int)blockIdx.x >= g1) {
        int wave = (blockIdx.x - g1) * (blockDim.x >> 6) + (threadIdx.x >> 6);
        int lane = threadIdx.x & 63;
        const v4i* p4 = reinterpret_cast<const v4i*>(ptn) + (size_t)wave * 1024;
        int c0=0,c1=0,c2=0,c3=0,c4=0,c5=0,c6=0,c7=0;
        for (int t = 0; t < 16; ++t) {
            v4i ia = __builtin_nontemporal_load(p4 + t*64 + lane);
            #pragma unroll
            for (int c = 0; c < 4; ++c) {
                int bin = ia[c] >> shift;
                #define CNTB(B, C) { unsigned long long m = __ballot(bin == B); C += (int)__popcll(m); }
                CNTB(0,c0) CNTB(1,c1) CNTB(2,c2) CNTB(3,c3)
                CNTB(4,c4) CNTB(5,c5) CNTB(6,c6) CNTB(7,c7)
                #undef CNTB
            }
        }
        int v = 0;
        if      (lane == 0) v = c0; else if (lane == 1) v = c1;
        else if (lane == 2) v = c2; else if (lane == 3) v = c3;
        else if (lane == 4) v = c4; else if (lane == 5) v = c5;
        else if (lane == 6) v = c6; else if (lane == 7) v = c7;
        if (lane < 8) counts[wave*8 + lane] = v;
        return;
    }
    int i = blockIdx.x * blockDim.x + threadIdx.x;
    if (i > N) return;
    if (i == N) { int2 p; p.x = N; p.y = __float_as_int(0.0f); packed[N] = p; return; }
    const v2f* a2 = reinterpret_cast<const v2f*>(attrs + (size_t)i * 6);
    v2f a0  = __builtin_nontemporal_load(a2 + 0);
    v2f a1  = __builtin_nontemporal_load(a2 + 1);
    v2f a2v = __builtin_nontemporal_load(a2 + 2);
    float logit = bias[0]
                + a0.x  * w[0] + a0.y  * w[1]
                + a1.x  * w[2] + a1.y  * w[3]
                + a2v.x * w[4] + a2v.y * w[5];
    float s = fminf(fmaxf(100.0f * logit, -12.0f), 12.0f);
    float gate = 1.0f / (1.0f + __expf(-s));
    float vv = gate * __builtin_nontemporal_load(residue + i);
    int2 p; p.x = __builtin_nontemporal_load(parent + i); p.y = __float_as_int(vv);
    packed[i] = p;
}

// ---------------- scan body (1 block, 256 thr): 64-aligned bin starts ---------
__device__ void scan_body(const int* __restrict__ counts, int* __restrict__ bases,
                          int* __restrict__ binStart, int* __restrict__ binCnt,
                          int nWaves) {
    int tid = threadIdx.x;
    int b = tid >> 5;            // 8 bins x 32 lanes
    int l = tid & 31;
    int g = nWaves >> 5;
    int w0 = l * g;
    int sum = 0;
    for (int w = w0; w < w0 + g; ++w) sum += counts[w*8 + b];
    int inc = sum;
    #pragma unroll
    for (int d = 1; d < 32; d <<= 1) {
        int o = __shfl_up(inc, d);
        if (l >= d) inc += o;
    }
    int excl = inc - sum;
    __shared__ int totals[8];
    __shared__ int bstart[9];
    if (l == 31) totals[b] = inc;
    __syncthreads();
    if (tid == 0) {
        bstart[0] = 0;
        for (int i = 0; i < 8; ++i) {
            binCnt[i] = totals[i];
            bstart[i+1] = bstart[i] + ((totals[i] + 63) & ~63);
        }
        for (int i = 0; i < 9; ++i) binStart[i] = bstart[i];
    }
    __syncthreads();
    int run = bstart[b] + excl;
    for (int w = w0; w < w0 + g; ++w) { bases[w*8 + b] = run; run += counts[w*8 + b]; }
}

// ---------------- B: fused walk L0 | scan -------------------------------------
__global__ void k_walk0_scan(const int2* __restrict__ packed,
                             float* __restrict__ cum, int hi, int N,
                             const int* __restrict__ counts, int* __restrict__ bases,
                             int* __restrict__ binStart, int* __restrict__ binCnt,
                             int nWaves) {
    if (blockIdx.x == 0) { scan_body(counts, bases, binStart, binCnt, nWaves); return; }
    int i = (blockIdx.x - 1) * blockDim.x + threadIdx.x;
    if (i >= hi) return;
    float s = 0.0f; int j = i;
    while (j != N) { int2 pv = packed[j]; s += __int_as_float(pv.y); j = pv.x; }
    cum[i] = s;
}

__global__ void k_walk_lvl0(const int2* __restrict__ packed,
                            float* __restrict__ cum, int hi, int N) {
    int i = blockIdx.x * blockDim.x + threadIdx.x;
    if (i >= hi) return;
    float s = 0.0f; int j = i;
    while (j != N) { int2 pv = packed[j]; s += __int_as_float(pv.y); j = pv.x; }
    cum[i] = s;
}

__global__ void k_walk_lvl(const int2* __restrict__ packed,
                           float* __restrict__ cum, int lo, int hi, int cutoff) {
    int i = lo + blockIdx.x * blockDim.x + threadIdx.x;
    if (i >= hi) return;
    float s = 0.0f; int j = i;
    do { int2 pv = packed[j]; s += __int_as_float(pv.y); j = pv.x; } while (j >= cutoff);
    cum[i] = s + cum[j];
}

// ---------------- scatter body ------------------------------------------------
__device__ void scatter_body(const int* __restrict__ ptn,
                             const int* __restrict__ bases,
                             int* __restrict__ nodes_b, int shift, int bid) {
    int wave = bid * (blockDim.x >> 6) + (threadIdx.x >> 6);
    int lane = threadIdx.x & 63;
    unsigned long long lt = (1ull << lane) - 1ull;
    const v4i* p4 = reinterpret_cast<const v4i*>(ptn) + (size_t)wave * 1024;
    int mybase = (lane < 8) ? bases[wave*8 + lane] : 0;
    int w0=0,w1=0,w2=0,w3=0,w4=0,w5=0,w6=0,w7=0;
    for (int t = 0; t < 16; ++t) {
        v4i ia = __builtin_nontemporal_load(p4 + t*64 + lane);
        #pragma unroll
        for (int c = 0; c < 4; ++c) {
            int node = ia[c];
            int bin = node >> shift;
            int off = 0;
            #define STEPB(B, W) { unsigned long long m = __ballot(bin == B); \
                if (bin == B) off = W + (int)__popcll(m & lt); W += (int)__popcll(m); }
            STEPB(0,w0) STEPB(1,w1) STEPB(2,w2) STEPB(3,w3)
            STEPB(4,w4) STEPB(5,w5) STEPB(6,w6) STEPB(7,w7)
            #undef STEPB
            int gbase = __shfl(mybase, bin);
            nodes_b[gbase + off] = node;
        }
    }
}

// ---------------- C: fused scatter | walk L1 ----------------------------------
__global__ void k_scatter_walk1(const int* __restrict__ ptn,
                                const int* __restrict__ bases,
                                int* __restrict__ nodes_b, int shift, int gS,
                                const int2* __restrict__ packed,
                                float* __restrict__ cum, int lo, int hi, int cutoff) {
    if ((int)blockIdx.x < gS) { scatter_body(ptn, bases, nodes_b, shift, blockIdx.x); return; }
    int i = lo + (blockIdx.x - gS) * blockDim.x + threadIdx.x;
    if (i >= hi) return;
    float s = 0.0f; int j = i;
    do { int2 pv = packed[j]; s += __int_as_float(pv.y); j = pv.x; } while (j >= cutoff);
    cum[i] = s + cum[j];
}

// ---------------- gather body: ILP-8, in-place (index -> value) ---------------
__device__ void gather_body(int* __restrict__ nv, const float* __restrict__ cum,
                            const int* __restrict__ binStart,
                            const int* __restrict__ binCnt,
                            int binLo, int nBins, int blocksPerBin, int g) {
    int b = binLo + g % nBins;
    int s = binStart[b];                 // multiple of 64 -> v4i aligned
    int cnt = binCnt[b];
    int nq = cnt >> 2;
    int T = blocksPerBin * blockDim.x;
    int q0 = (g / nBins) * blockDim.x + threadIdx.x;
    v4i* np = reinterpret_cast<v4i*>(nv + s);
    int q = q0;
    for (; q + T < nq; q += 2 * T) {
        v4i na = __builtin_nontemporal_load(np + q);
        v4i nb = __builtin_nontemporal_load(np + q + T);
        v4f va, vb;                      // 8 independent gathers in flight
        va.x = cum[na.x]; va.y = cum[na.y]; va.z = cum[na.z]; va.w = cum[na.w];
        vb.x = cum[nb.x]; vb.y = cum[nb.y]; vb.z = cum[nb.z]; vb.w = cum[nb.w];
        reinterpret_cast<v4f*>(np)[q]     = va;   // in-place: same thread, same slot
        reinterpret_cast<v4f*>(np)[q + T] = vb;
    }
    for (; q < nq; q += T) {
        v4i na = __builtin_nontemporal_load(np + q);
        v4f va;
        va.x = cum[na.x]; va.y = cum[na.y]; va.z = cum[na.z]; va.w = cum[na.w];
        reinterpret_cast<v4f*>(np)[q] = va;
    }
    if (q0 < (cnt & 3)) {
        int i = s + nq * 4 + q0;
        float v = cum[nv[i]];
        reinterpret_cast<float*>(nv)[i] = v;
    }
}

// ---------------- E: fused walk L3 | gather bins [0, nEarly) ------------------
__global__ __launch_bounds__(256) void k_walk3_gather(
        const int2* __restrict__ packed, float* __restrict__ cum,
        int lo, int hi, int cutoff, int gW3,
        int* __restrict__ nv, const int* __restrict__ binStart,
        const int* __restrict__ binCnt, int nEarly, int blocksPerBin) {
    if ((int)blockIdx.x >= gW3) {
        gather_body(nv, cum, binStart, binCnt, 0, nEarly, blocksPerBin,
                    blockIdx.x - gW3);
        return;
    }
    int i = lo + blockIdx.x * blockDim.x + threadIdx.x;
    if (i >= hi) return;
    float s = 0.0f; int j = i;
    do { int2 pv = packed[j]; s += __int_as_float(pv.y); j = pv.x; } while (j >= cutoff);
    cum[i] = s + cum[j];
}

// ---------------- F: gather bins [binLo, 8) -----------------------------------
__global__ __launch_bounds__(256) void k_gather(int* __restrict__ nv,
                                                const float* __restrict__ cum,
                                                const int* __restrict__ binStart,
                                                const int* __restrict__ binCnt,
                                                int binLo, int nBins, int blocksPerBin) {
    gather_body(nv, cum, binStart, binCnt, binLo, nBins, blocksPerBin, blockIdx.x);
}

// ---------------- G: merge back in pixel order --------------------------------
__global__ void k_merge(const int* __restrict__ ptn, const int* __restrict__ bases,
                        const float* __restrict__ vals_b, float* __restrict__ out,
                        int shift) {
    int wave = blockIdx.x * (blockDim.x >> 6) + (threadIdx.x >> 6);
    int lane = threadIdx.x & 63;
    unsigned long long lt = (1ull << lane) - 1ull;
    const v4i* p4 = reinterpret_cast<const v4i*>(ptn) + (size_t)wave * 1024;
    int mybase = (lane < 8) ? bases[wave*8 + lane] : 0;
    int w0=0,w1=0,w2=0,w3=0,w4=0,w5=0,w6=0,w7=0;
    for (int t = 0; t < 16; ++t) {
        v4i ia = __builtin_nontemporal_load(p4 + t*64 + lane);
        v4f o;
        #pragma unroll
        for (int c = 0; c < 4; ++c) {
            int bin = ia[c] >> shift;
            int off = 0;
            #define STEPB(B, W) { unsigned long long m = __ballot(bin == B); \
                if (bin == B) off = W + (int)__popcll(m & lt); W += (int)__popcll(m); }
            STEPB(0,w0) STEPB(1,w1) STEPB(2,w2) STEPB(3,w3)
            STEPB(4,w4) STEPB(5,w5) STEPB(6,w6) STEPB(7,w7)
            #undef STEPB
            int gbase = __shfl(mybase, bin);
            o[c] = vals_b[gbase + off];
        }
        reinterpret_cast<v4f*>(out)[(size_t)wave * 1024 + t*64 + lane] = o;
    }
}

// ---------------- Fallback: direct pixel gather -------------------------------
__global__ void k_pixel_gather(const float* __restrict__ cum,
                               const int* __restrict__ ptn,
                               float* __restrict__ out, int M) {
    int t = blockIdx.x * blockDim.x + threadIdx.x;
    int base = t * 4;
    if (base + 3 < M) {
        v4i idx = __builtin_nontemporal_load(reinterpret_cast<const v4i*>(ptn) + t);
        float4 o;
        o.x = cum[idx.x]; o.y = cum[idx.y]; o.z = cum[idx.z]; o.w = cum[idx.w];
        reinterpret_cast<float4*>(out)[t] = o;
    } else {
        for (int p = base; p < M; ++p) out[p] = cum[ptn[p]];
    }
}

extern "C" void kernel_launch(void* const* d_in, const int* in_sizes, int n_in,
                              void* d_out, int out_size, void* d_ws, size_t ws_size,
                              hipStream_t stream) {
    const float* attrs   = (const float*)d_in[0];
    const float* weight  = (const float*)d_in[1];
    const float* bias    = (const float*)d_in[2];
    const float* residue = (const float*)d_in[3];
    const int*   parent  = (const int*)d_in[4];
    const int*   ptn     = (const int*)d_in[5];
    float* out = (float*)d_out;

    const int N  = in_sizes[3];
    const int HW = in_sizes[5];
    const int BLK = 256;

    auto align256 = [](size_t x) { return (x + 255) & ~(size_t)255; };
    const size_t cumB    = align256((size_t)(N + 1) * 4);
    const size_t packedB = align256((size_t)(N + 1) * 8);
    const size_t nvB     = align256(((size_t)HW + 512) * 4);
    const int nWaves = HW / 4096;
    const size_t cntB = align256((size_t)nWaves * 8 * 4);
    const size_t needBinned = cumB + packedB + nvB + 2 * cntB + 256;

    float* cum    = (float*)d_ws;
    int2*  packed = (int2*)((char*)d_ws + cumB);
    int*   nv     = (int*)((char*)d_ws + cumB + packedB);
    int*   counts = (int*)((char*)d_ws + cumB + packedB + nvB);
    int*   bases  = (int*)((char*)d_ws + cumB + packedB + nvB + cntB);
    int*   binStart = (int*)((char*)d_ws + cumB + packedB + nvB + 2 * cntB);
    int*   binCnt   = binStart + 16;

    bool binnedOK = (HW % 4096 == 0) && (nWaves % 64 == 0) && (nWaves >= 64) &&
                    (ws_size >= needBinned) && (N > 8);

    int shift = 0;
    while (((long)(N - 1) >> shift) > 7) ++shift;   // 8 bins cover [0,N)

    // A) fused gate+pack | count
    int g1 = (N + 1 + BLK - 1) / BLK;
    int gWave = binnedOK ? (nWaves / 4) : 0;
    k_gate_count<<<g1 + gWave, BLK, 0, stream>>>(attrs, weight, bias, residue,
                                                 parent, packed, N,
                                                 ptn, counts, shift, g1);

    // walk cutoffs 16K / 256K / 1M / N
    int c0 = 16384;   if (c0 > N) c0 = N;
    int c1 = 262144;  if (c1 > N) c1 = N;
    int c2 = 1048576; if (c2 > N) c2 = N;

    if (binnedOK) {
        // B) walk L0 | scan
        int g20 = (c0 + BLK - 1) / BLK;
        k_walk0_scan<<<g20 + 1, BLK, 0, stream>>>(packed, cum, c0, N,
                                                  counts, bases, binStart, binCnt,
                                                  nWaves);
        // C) scatter | walk L1
        int gS = nWaves / 4;
        int gW1 = (c1 > c0) ? (c1 - c0 + BLK - 1) / BLK : 0;
        k_scatter_walk1<<<gS + gW1, BLK, 0, stream>>>(ptn, bases, nv, shift, gS,
                                                      packed, cum, c0, c1, c0);
        // D) walk L2
        if (c2 > c1)
            k_walk_lvl<<<(c2 - c1 + BLK - 1) / BLK, BLK, 0, stream>>>(packed, cum, c1, c2, c1);

        // bins [0, nEarly) only touch cum[< c2]: complete after D
        int nEarly = c2 >> shift; if (nEarly > 8) nEarly = 8;
        if (N <= c2) nEarly = 8;   // no walk3 -> everything ready
        const int BPB = 256;       // blocks per bin

        // E) walk L3 | gather bins [0, nEarly)
        int gW3 = (N > c2) ? (N - c2 + BLK - 1) / BLK : 0;
        int gE = (nEarly > 0) ? nEarly * BPB : 0;
        if (gW3 + gE > 0)
            k_walk3_gather<<<gW3 + gE, BLK, 0, stream>>>(packed, cum, c2, N, c2,
                                                         gW3, nv, binStart, binCnt,
                                                         nEarly, BPB);
        // F) gather bins [nEarly, 8)
        int nLate = 8 - nEarly;
        if (nLate > 0)
            k_gather<<<nLate * BPB, BLK, 0, stream>>>(nv, cum, binStart, binCnt,
                                                      nEarly, nLate, BPB);
        // G) merge
        k_merge<<<nWaves / 4, BLK, 0, stream>>>(ptn, bases, (const float*)nv, out, shift);
    } else {
        k_walk_lvl0<<<(c0 + BLK - 1) / BLK, BLK, 0, stream>>>(packed, cum, c0, N);
        if (c1 > c0)
            k_walk_lvl<<<(c1 - c0 + BLK - 1) / BLK, BLK, 0, stream>>>(packed, cum, c0, c1, c0);
        if (c2 > c1)
            k_walk_lvl<<<(c2 - c1 + BLK - 1) / BLK, BLK, 0, stream>>>(packed, cum, c1, c2, c1);
        if (N > c2)
            k_walk_lvl<<<(N - c2 + BLK - 1) / BLK, BLK, 0, stream>>>(packed, cum, c2, N, c2);
        int nQuads = (HW + 3) / 4;
        k_pixel_gather<<<(nQuads + BLK - 1) / BLK, BLK, 0, stream>>>(cum, ptn, out, HW);
    }
}

// Round 10
// 364.862 us; speedup vs baseline: 1.0570x; 1.0570x over previous
//
#include <hip/hip_runtime.h>
#include <hip/hip_bf16.h>

// Connected filter:
//   vals[i] = sigmoid(clamp(100*(attrs[i]·w + b), ±12)) * residue[i]
//   cum[i]  = sum of vals along parent chain from i (dummy N terminates)
//   out[p]  = cum[pixel_to_node[p]]
// parent[i] < i (topological), parent[N] = N (dummy, val 0).
//
// Pipeline: gate+pack | count512 -> scanA/B/C -> walks (16K/256K/1M/N)
//           -> scatter512 -> gather512 (LDS slice) -> merge512
// Key idea (R9): the 16M-random-gather is pinned at ~9 req/cy/XCD L2 wall
// (R6/R7 evidence). 512 bins x 8K-node slices -> gather reads come from a
// 32KB LDS-staged slice: all global traffic becomes streaming.
// Determinism: no atomics anywhere. Rank within wave via 9-ballot match-mask;
// per-wave LDS histograms; hierarchical scan (64 groups x 32 chunks).
// Lessons: nt-stores double WRITE_SIZE (never); partial-line scattered writes
// hit the request wall -> scatter stages in LDS, writes full runs; fusing two
// saturating phases = serialization (R8/R9) -> keep dispatches simple.

typedef float v2f __attribute__((ext_vector_type(2)));
typedef float v4f __attribute__((ext_vector_type(4)));
typedef int   v4i __attribute__((ext_vector_type(4)));

#define NB 512          // bin table size (bins = ((N-1)>>shift)+1 <= 512)
#define CHUNK_PX 8192   // pixels per chunk (= per block in count/scatter/merge)
#define CV4 2048        // v4i per chunk
#define WV4 512         // v4i per wave (4 waves per 256-thread block)
#define ITERS 8         // v4i iterations per lane

__device__ __forceinline__ unsigned long long match9(int bin) {
    unsigned long long m = ~0ull;
    #pragma unroll
    for (int k = 0; k < 9; ++k) {
        unsigned long long bk = __ballot(((bin >> k) & 1) != 0);
        m &= ((bin >> k) & 1) ? bk : ~bk;
    }
    return m;
}

// ---------------- A: fused gate+pack | per-wave 512-bin count -----------------
__global__ __launch_bounds__(256) void k_gate_count512(
        const float* __restrict__ attrs, const float* __restrict__ w,
        const float* __restrict__ bias, const float* __restrict__ residue,
        const int* __restrict__ parent, int2* __restrict__ packed, int N,
        const int* __restrict__ ptn, unsigned short* __restrict__ wcnt,
        int shift, int g1) {
    __shared__ int hist[4][NB];
    if ((int)blockIdx.x >= g1) {
        int chunk = blockIdx.x - g1;
        int tid = threadIdx.x, wave = tid >> 6, lane = tid & 63;
        for (int i = tid; i < 4*NB; i += 256) (&hist[0][0])[i] = 0;
        __syncthreads();
        const v4i* p4 = reinterpret_cast<const v4i*>(ptn) + (size_t)chunk*CV4 + wave*WV4;
        unsigned long long lt = (1ull << lane) - 1ull;
        for (int t = 0; t < ITERS; ++t) {
            v4i ia = __builtin_nontemporal_load(p4 + t*64 + lane);
            #pragma unroll
            for (int c = 0; c < 4; ++c) {
                int bin = ia[c] >> shift;
                unsigned long long m = match9(bin);
                if ((m & lt) == 0ull)                       // group leader
                    hist[wave][bin] += (int)__popcll(m);    // per-wave, non-atomic
            }
        }
        __syncthreads();
        unsigned short* wc = wcnt + (size_t)chunk * (4*NB);
        for (int i = tid; i < 4*NB; i += 256)
            wc[i] = (unsigned short)(&hist[0][0])[i];
        return;
    }
    int i = blockIdx.x * blockDim.x + threadIdx.x;
    if (i > N) return;
    if (i == N) { int2 p; p.x = N; p.y = __float_as_int(0.0f); packed[N] = p; return; }
    const v2f* a2 = reinterpret_cast<const v2f*>(attrs + (size_t)i * 6);
    v2f a0  = __builtin_nontemporal_load(a2 + 0);
    v2f a1  = __builtin_nontemporal_load(a2 + 1);
    v2f a2v = __builtin_nontemporal_load(a2 + 2);
    float logit = bias[0]
                + a0.x  * w[0] + a0.y  * w[1]
                + a1.x  * w[2] + a1.y  * w[3]
                + a2v.x * w[4] + a2v.y * w[5];
    float s = fminf(fmaxf(100.0f * logit, -12.0f), 12.0f);
    float gate = 1.0f / (1.0f + __expf(-s));
    float vv = gate * __builtin_nontemporal_load(residue + i);
    int2 p; p.x = __builtin_nontemporal_load(parent + i); p.y = __float_as_int(vv);
    packed[i] = p;
}

// ---------------- scan stage 1: group partials (32 chunks per group) ----------
__global__ __launch_bounds__(512) void k_scanA(const unsigned short* __restrict__ wcnt,
                                               int* __restrict__ P) {
    int g = blockIdx.x, b = threadIdx.x;
    const unsigned short* base = wcnt + (size_t)g * 32 * (4*NB);
    int s = 0;
    for (int i = 0; i < 32*4; ++i) s += base[(size_t)i*NB + b];
    P[(size_t)g*NB + b] = s;
}

// ---------------- scan stage 2: bin totals + 64-aligned bin starts ------------
__global__ __launch_bounds__(512) void k_scanB(int* __restrict__ P,
                                               int* __restrict__ binStart,
                                               int* __restrict__ binCnt, int nGroups) {
    int b = threadIdx.x, lane = b & 63, wave = b >> 6;
    int tot = 0;
    for (int g = 0; g < nGroups; ++g) {
        int t = P[(size_t)g*NB + b]; P[(size_t)g*NB + b] = tot; tot += t;  // excl in place
    }
    binCnt[b] = tot;
    int pad = (tot + 63) & ~63;
    int inc = pad;
    #pragma unroll
    for (int d = 1; d < 64; d <<= 1) { int o = __shfl_up(inc, d); if (lane >= d) inc += o; }
    __shared__ int wsum[8];
    if (lane == 63) wsum[wave] = inc;
    __syncthreads();
    int wb = 0;
    for (int ww = 0; ww < wave; ++ww) wb += wsum[ww];
    binStart[b] = wb + inc - pad;
}

// ---------------- scan stage 3: per-chunk bases -------------------------------
__global__ __launch_bounds__(512) void k_scanC(const unsigned short* __restrict__ wcnt,
                                               const int* __restrict__ P,
                                               const int* __restrict__ binStart,
                                               int* __restrict__ bases) {
    int g = blockIdx.x, b = threadIdx.x;
    int run = binStart[b] + P[(size_t)g*NB + b];
    for (int i = 0; i < 32; ++i) {
        size_t c = (size_t)g*32 + i;
        bases[c*NB + b] = run;
        const unsigned short* wc = wcnt + c * (4*NB);
        run += wc[0*NB+b] + wc[1*NB+b] + wc[2*NB+b] + wc[3*NB+b];
    }
}

// ---------------- walks (cutoffs 16K/256K/1M/N) -------------------------------
__global__ void k_walk_lvl0(const int2* __restrict__ packed,
                            float* __restrict__ cum, int hi, int N) {
    int i = blockIdx.x * blockDim.x + threadIdx.x;
    if (i >= hi) return;
    float s = 0.0f; int j = i;
    while (j != N) { int2 pv = packed[j]; s += __int_as_float(pv.y); j = pv.x; }
    cum[i] = s;
}

__global__ void k_walk_lvl(const int2* __restrict__ packed,
                           float* __restrict__ cum, int lo, int hi, int cutoff) {
    int i = lo + blockIdx.x * blockDim.x + threadIdx.x;
    if (i >= hi) return;
    float s = 0.0f; int j = i;
    do { int2 pv = packed[j]; s += __int_as_float(pv.y); j = pv.x; } while (j >= cutoff);
    cum[i] = s + cum[j];
}

// ---------------- scatter: deterministic rank, LDS-staged, run writes ---------
__global__ __launch_bounds__(256) void k_scatter512(
        const int* __restrict__ ptn, const unsigned short* __restrict__ wcnt,
        const int* __restrict__ bases, int* __restrict__ nv,
        unsigned short* __restrict__ slotLocal, int shift) {
    __shared__ int hist[4][NB];
    __shared__ int chEx[NB];
    __shared__ int btot[NB];
    __shared__ int ldss[CHUNK_PX];
    __shared__ int wsum[4];
    int chunk = blockIdx.x;
    int tid = threadIdx.x, wave = tid >> 6, lane = tid & 63;
    const unsigned short* wc = wcnt + (size_t)chunk * (4*NB);
    for (int i = tid; i < 4*NB; i += 256) (&hist[0][0])[i] = wc[i];
    __syncthreads();
    // wave-exclusive within (chunk,bin) + chunk totals
    for (int b = tid; b < NB; b += 256) {
        int t0 = hist[0][b], t1 = hist[1][b], t2 = hist[2][b], t3 = hist[3][b];
        hist[0][b] = 0; hist[1][b] = t0; hist[2][b] = t0+t1; hist[3][b] = t0+t1+t2;
        btot[b] = t0+t1+t2+t3;
    }
    __syncthreads();
    // chunk-local exclusive scan over bins (2 bins per thread)
    {
        int b0 = 2*tid;
        int s0 = btot[b0], s1 = btot[b0+1], s = s0 + s1;
        int inc = s;
        #pragma unroll
        for (int d = 1; d < 64; d <<= 1) { int o = __shfl_up(inc, d); if (lane >= d) inc += o; }
        if (lane == 63) wsum[wave] = inc;
        __syncthreads();
        int wb = 0;
        for (int ww = 0; ww < wave; ++ww) wb += wsum[ww];
        int ex = wb + inc - s;
        chEx[b0] = ex; chEx[b0+1] = ex + s0;
    }
    __syncthreads();
    // rank + LDS scatter + slotLocal (13-bit chunk-local slot, u16x4 packed)
    const v4i* p4 = reinterpret_cast<const v4i*>(ptn) + (size_t)chunk*CV4 + wave*WV4;
    unsigned long long lt = (1ull << lane) - 1ull;
    unsigned long long* sl8 = reinterpret_cast<unsigned long long*>(slotLocal)
                              + (size_t)chunk*CV4 + wave*WV4;
    for (int t = 0; t < ITERS; ++t) {
        v4i ia = __builtin_nontemporal_load(p4 + t*64 + lane);
        unsigned long long pk = 0;
        #pragma unroll
        for (int c = 0; c < 4; ++c) {
            int node = ia[c];
            int bin = node >> shift;
            unsigned long long m = match9(bin);
            int rank = (int)__popcll(m & lt);
            int base = hist[wave][bin];               // all group lanes read
            if (rank == 0) hist[wave][bin] = base + (int)__popcll(m);  // leader advances
            int slot = chEx[bin] + base + rank;       // < 8192
            ldss[slot] = node;
            pk |= (unsigned long long)(unsigned)slot << (16*c);
        }
        sl8[t*64 + lane] = pk;
    }
    __syncthreads();
    // write bin-sorted chunk out as contiguous runs (full-line writes)
    for (int b = tid; b < NB; b += 256) {
        int n = btot[b];
        int src = chEx[b];
        int dst = bases[(size_t)chunk*NB + b];
        for (int i = 0; i < n; ++i)
            nv[dst + i] = ldss[src + i];
    }
}

// ---------------- gather: LDS-staged 32KB cum slice, in-place int->float ------
__global__ __launch_bounds__(512) void k_gather512(
        int* __restrict__ nv, const float* __restrict__ cum,
        const int* __restrict__ binStart, const int* __restrict__ binCnt,
        int shift, int N) {
    __shared__ float slice[8192];
    int b = blockIdx.x;
    int base = b << shift;
    int W = 1 << shift;
    for (int i = threadIdx.x; i < W; i += 512) {
        int idx = base + i;
        slice[i] = (idx < N) ? cum[idx] : 0.0f;
    }
    __syncthreads();
    int s = binStart[b], cnt = binCnt[b];
    int nq = cnt >> 2;
    v4i* np = reinterpret_cast<v4i*>(nv + s);      // 64-aligned starts
    v4f* vp = reinterpret_cast<v4f*>(nv + s);
    for (int q = threadIdx.x; q < nq; q += 512) {
        v4i na = __builtin_nontemporal_load(np + q);
        v4f va;
        va.x = slice[na.x - base];
        va.y = slice[na.y - base];
        va.z = slice[na.z - base];
        va.w = slice[na.w - base];
        vp[q] = va;                                 // in-place: same thread, same slot
    }
    int r = cnt & 3;
    if ((int)threadIdx.x < r) {
        int i = s + nq*4 + threadIdx.x;
        float v = slice[nv[i] - base];
        reinterpret_cast<float*>(nv)[i] = v;
    }
}

// ---------------- merge: stream runs into LDS, resolve via slotLocal ----------
__global__ __launch_bounds__(256) void k_merge512(
        const unsigned short* __restrict__ wcnt, const int* __restrict__ bases,
        const float* __restrict__ nvf, const unsigned short* __restrict__ slotLocal,
        float* __restrict__ out) {
    __shared__ float ldsv[CHUNK_PX];
    __shared__ int chEx[NB];
    __shared__ int cnts[NB];
    __shared__ int wsum[4];
    int chunk = blockIdx.x;
    int tid = threadIdx.x, wave = tid >> 6, lane = tid & 63;
    const unsigned short* wc = wcnt + (size_t)chunk * (4*NB);
    for (int b = tid; b < NB; b += 256)
        cnts[b] = wc[0*NB+b] + wc[1*NB+b] + wc[2*NB+b] + wc[3*NB+b];
    __syncthreads();
    {
        int b0 = 2*tid;
        int s0 = cnts[b0], s1 = cnts[b0+1], s = s0 + s1;
        int inc = s;
        #pragma unroll
        for (int d = 1; d < 64; d <<= 1) { int o = __shfl_up(inc, d); if (lane >= d) inc += o; }
        if (lane == 63) wsum[wave] = inc;
        __syncthreads();
        int wb = 0;
        for (int ww = 0; ww < wave; ++ww) wb += wsum[ww];
        int ex = wb + inc - s;
        chEx[b0] = ex; chEx[b0+1] = ex + s0;
    }
    __syncthreads();
    for (int b = tid; b < NB; b += 256) {       // copy this chunk's runs into LDS
        int n = cnts[b];
        int dst = chEx[b];
        int src = bases[(size_t)chunk*NB + b];
        for (int i = 0; i < n; ++i)
            ldsv[dst + i] = nvf[src + i];
    }
    __syncthreads();
    const unsigned long long* sl8 = reinterpret_cast<const unsigned long long*>(slotLocal)
                                    + (size_t)chunk*CV4 + wave*WV4;
    v4f* o4 = reinterpret_cast<v4f*>(out) + (size_t)chunk*CV4 + wave*WV4;
    for (int t = 0; t < ITERS; ++t) {
        unsigned long long pk = __builtin_nontemporal_load(sl8 + t*64 + lane);
        v4f o;
        o.x = ldsv[pk & 0xFFFF];
        o.y = ldsv[(pk >> 16) & 0xFFFF];
        o.z = ldsv[(pk >> 32) & 0xFFFF];
        o.w = ldsv[(pk >> 48) & 0xFFFF];
        o4[t*64 + lane] = o;                    // coalesced pixel-order write
    }
}

// ---------------- fallback: direct pixel gather -------------------------------
__global__ void k_pixel_gather(const float* __restrict__ cum,
                               const int* __restrict__ ptn,
                               float* __restrict__ out, int M) {
    int t = blockIdx.x * blockDim.x + threadIdx.x;
    int base = t * 4;
    if (base + 3 < M) {
        v4i idx = __builtin_nontemporal_load(reinterpret_cast<const v4i*>(ptn) + t);
        float4 o;
        o.x = cum[idx.x]; o.y = cum[idx.y]; o.z = cum[idx.z]; o.w = cum[idx.w];
        reinterpret_cast<float4*>(out)[t] = o;
    } else {
        for (int p = base; p < M; ++p) out[p] = cum[ptn[p]];
    }
}

extern "C" void kernel_launch(void* const* d_in, const int* in_sizes, int n_in,
                              void* d_out, int out_size, void* d_ws, size_t ws_size,
                              hipStream_t stream) {
    const float* attrs   = (const float*)d_in[0];
    const float* weight  = (const float*)d_in[1];
    const float* bias    = (const float*)d_in[2];
    const float* residue = (const float*)d_in[3];
    const int*   parent  = (const int*)d_in[4];
    const int*   ptn     = (const int*)d_in[5];
    float* out = (float*)d_out;

    const int N  = in_sizes[3];
    const int HW = in_sizes[5];
    const int BLK = 256;

    int shift = 0;
    while (((long)(N - 1) >> shift) >= NB) ++shift;
    int nBins = (int)(((long)(N - 1) >> shift) + 1);

    const int nChunks = HW / CHUNK_PX;
    const int nGroups = nChunks / 32;

    auto align256 = [](size_t x) { return (x + 255) & ~(size_t)255; };
    const size_t cumB   = align256((size_t)(N + 1) * 4);
    const size_t pkB    = (size_t)(N + 1) * 8;
    const size_t slB    = (size_t)HW * 2;
    const size_t regA   = align256(pkB > slB ? pkB : slB);     // packed / slotLocal alias
    const size_t nvB    = align256(((size_t)HW + (size_t)NB*64) * 4);
    const size_t wcntB  = align256((size_t)nChunks * 4*NB * 2);
    const size_t PB     = align256((size_t)nGroups * NB * 4);
    const size_t basesB = align256((size_t)nChunks * NB * 4);
    const size_t need   = cumB + regA + nvB + wcntB + PB + basesB + 4096;

    float* cum    = (float*)d_ws;
    int2*  packed = (int2*)((char*)d_ws + cumB);
    unsigned short* slotLocal = (unsigned short*)((char*)d_ws + cumB);  // alias (packed dead)
    int*   nv     = (int*)((char*)d_ws + cumB + regA);
    unsigned short* wcnt = (unsigned short*)((char*)d_ws + cumB + regA + nvB);
    int*   P      = (int*)((char*)d_ws + cumB + regA + nvB + wcntB);
    int*   bases  = (int*)((char*)d_ws + cumB + regA + nvB + wcntB + PB);
    int*   binStart = (int*)((char*)d_ws + cumB + regA + nvB + wcntB + PB + basesB);
    int*   binCnt   = binStart + NB;

    bool binnedOK = (HW % CHUNK_PX == 0) && (nChunks % 32 == 0) && (nChunks >= 32) &&
                    (shift <= 13) && (ws_size >= need) && (N >= 2);

    // A) gate+pack | count512
    int g1 = (N + 1 + BLK - 1) / BLK;
    int gC = binnedOK ? nChunks : 0;
    k_gate_count512<<<g1 + gC, BLK, 0, stream>>>(attrs, weight, bias, residue,
                                                 parent, packed, N,
                                                 ptn, wcnt, shift, g1);

    if (binnedOK) {
        k_scanA<<<nGroups, 512, 0, stream>>>(wcnt, P);
        k_scanB<<<1, 512, 0, stream>>>(P, binStart, binCnt, nGroups);
        k_scanC<<<nGroups, 512, 0, stream>>>(wcnt, P, binStart, bases);
    }

    // walks: cutoffs 16K / 256K / 1M / N
    int c0 = 16384;   if (c0 > N) c0 = N;
    int c1 = 262144;  if (c1 > N) c1 = N;
    int c2 = 1048576; if (c2 > N) c2 = N;

    k_walk_lvl0<<<(c0 + BLK - 1) / BLK, BLK, 0, stream>>>(packed, cum, c0, N);
    if (c1 > c0)
        k_walk_lvl<<<(c1 - c0 + BLK - 1) / BLK, BLK, 0, stream>>>(packed, cum, c0, c1, c0);
    if (c2 > c1)
        k_walk_lvl<<<(c2 - c1 + BLK - 1) / BLK, BLK, 0, stream>>>(packed, cum, c1, c2, c1);
    if (N > c2)
        k_walk_lvl<<<(N - c2 + BLK - 1) / BLK, BLK, 0, stream>>>(packed, cum, c2, N, c2);

    if (binnedOK) {
        // packed is dead from here on; slotLocal reuses its region
        k_scatter512<<<nChunks, BLK, 0, stream>>>(ptn, wcnt, bases, nv, slotLocal, shift);
        k_gather512<<<nBins, 512, 0, stream>>>(nv, cum, binStart, binCnt, shift, N);
        k_merge512<<<nChunks, BLK, 0, stream>>>(wcnt, bases, (const float*)nv,
                                                slotLocal, out);
    } else {
        int nQuads = (HW + 3) / 4;
        k_pixel_gather<<<(nQuads + BLK - 1) / BLK, BLK, 0, stream>>>(cum, ptn, out, HW);
    }
}

// Round 11
// 314.371 us; speedup vs baseline: 1.2267x; 1.1606x over previous
//
#include <hip/hip_runtime.h>
#include <hip/hip_bf16.h>

// Connected filter:
//   vals[i] = sigmoid(clamp(100*(attrs[i]·w + b), ±12)) * residue[i]
//   cum[i]  = sum of vals along parent chain from i (dummy N terminates)
//   out[p]  = cum[pixel_to_node[p]]
// parent[i] < i (topological), parent[N] = N (dummy, val 0).
//
// Pipeline: gate+pack | count512 -> scanA/B/C -> walks (16K/256K/1M/N)
//           -> scatter512 -> gather512 (LDS cum slice) -> merge512
// R9 insight: 16M random gathers pinned at ~9 req/cy/XCD L2 wall -> 512 bins
// of 8K nodes; gather reads from a 32KB LDS slice; all global traffic streams.
// R10 insight: rank determinism is NOT needed for output determinism — each
// pixel reads its own recorded slot, so LDS atomicAdd ranks give bit-identical
// out regardless of ordering. match9 (35 VALU/elem) -> 1 ds_add. bin(slot) is
// derivable as ldss[slot]>>shift (drop 16KB sbin; scatter LDS 38KB, 4 blk/CU).
// Lessons: nt-stores double WRITE_SIZE; partial-line scattered writes hit the
// request wall -> LDS-stage and write runs; fused block-range "overlap" of two
// saturating phases serializes (R8/R9) -> keep dispatches simple.

typedef float v2f __attribute__((ext_vector_type(2)));
typedef float v4f __attribute__((ext_vector_type(4)));
typedef int   v4i __attribute__((ext_vector_type(4)));

#define NB 512          // bins; bin width 1<<shift <= 8192 nodes (32KB slice)
#define CHUNK_PX 8192   // pixels per chunk block
#define CV4 2048        // v4i quads per chunk

// ---------------- A: fused gate+pack | per-chunk histogram (LDS atomics) ------
__global__ __launch_bounds__(256) void k_gate_count512(
        const float* __restrict__ attrs, const float* __restrict__ w,
        const float* __restrict__ bias, const float* __restrict__ residue,
        const int* __restrict__ parent, int2* __restrict__ packed, int N,
        const int* __restrict__ ptn, unsigned short* __restrict__ wcnt,
        int shift, int g1) {
    __shared__ int hist[NB];
    if ((int)blockIdx.x >= g1) {
        int chunk = blockIdx.x - g1;
        int tid = threadIdx.x;
        for (int i = tid; i < NB; i += 256) hist[i] = 0;
        __syncthreads();
        const v4i* p4 = reinterpret_cast<const v4i*>(ptn) + (size_t)chunk * CV4;
        for (int t = 0; t < CV4/256; ++t) {
            v4i ia = __builtin_nontemporal_load(p4 + t*256 + tid);
            atomicAdd(&hist[ia.x >> shift], 1);
            atomicAdd(&hist[ia.y >> shift], 1);
            atomicAdd(&hist[ia.z >> shift], 1);
            atomicAdd(&hist[ia.w >> shift], 1);
        }
        __syncthreads();
        unsigned short* wc = wcnt + (size_t)chunk * NB;
        for (int i = tid; i < NB; i += 256) wc[i] = (unsigned short)hist[i];
        return;
    }
    int i = blockIdx.x * blockDim.x + threadIdx.x;
    if (i > N) return;
    if (i == N) { int2 p; p.x = N; p.y = __float_as_int(0.0f); packed[N] = p; return; }
    const v2f* a2 = reinterpret_cast<const v2f*>(attrs + (size_t)i * 6);
    v2f a0  = __builtin_nontemporal_load(a2 + 0);
    v2f a1  = __builtin_nontemporal_load(a2 + 1);
    v2f a2v = __builtin_nontemporal_load(a2 + 2);
    float logit = bias[0]
                + a0.x  * w[0] + a0.y  * w[1]
                + a1.x  * w[2] + a1.y  * w[3]
                + a2v.x * w[4] + a2v.y * w[5];
    float s = fminf(fmaxf(100.0f * logit, -12.0f), 12.0f);
    float gate = 1.0f / (1.0f + __expf(-s));
    float vv = gate * __builtin_nontemporal_load(residue + i);
    int2 p; p.x = __builtin_nontemporal_load(parent + i); p.y = __float_as_int(vv);
    packed[i] = p;
}

// ---------------- scan stage 1: group partials (32 chunks per group) ----------
__global__ __launch_bounds__(512) void k_scanA(const unsigned short* __restrict__ wcnt,
                                               int* __restrict__ P) {
    int g = blockIdx.x, b = threadIdx.x;
    const unsigned short* base = wcnt + (size_t)g * 32 * NB;
    int s = 0;
    for (int i = 0; i < 32; ++i) s += base[(size_t)i*NB + b];
    P[(size_t)g*NB + b] = s;
}

// ---------------- scan stage 2: bin totals + 64-aligned bin starts ------------
__global__ __launch_bounds__(512) void k_scanB(int* __restrict__ P,
                                               int* __restrict__ binStart,
                                               int* __restrict__ binCnt, int nGroups) {
    int b = threadIdx.x, lane = b & 63, wave = b >> 6;
    int tot = 0;
    for (int g = 0; g < nGroups; ++g) {
        int t = P[(size_t)g*NB + b]; P[(size_t)g*NB + b] = tot; tot += t;  // excl in place
    }
    binCnt[b] = tot;
    int pad = (tot + 63) & ~63;
    int inc = pad;
    #pragma unroll
    for (int d = 1; d < 64; d <<= 1) { int o = __shfl_up(inc, d); if (lane >= d) inc += o; }
    __shared__ int wsum[8];
    if (lane == 63) wsum[wave] = inc;
    __syncthreads();
    int wb = 0;
    for (int ww = 0; ww < wave; ++ww) wb += wsum[ww];
    binStart[b] = wb + inc - pad;
}

// ---------------- scan stage 3: per-chunk bases -------------------------------
__global__ __launch_bounds__(512) void k_scanC(const unsigned short* __restrict__ wcnt,
                                               const int* __restrict__ P,
                                               const int* __restrict__ binStart,
                                               int* __restrict__ bases) {
    int g = blockIdx.x, b = threadIdx.x;
    int run = binStart[b] + P[(size_t)g*NB + b];
    for (int i = 0; i < 32; ++i) {
        size_t c = (size_t)g*32 + i;
        bases[c*NB + b] = run;
        run += wcnt[c*NB + b];
    }
}

// ---------------- walks (cutoffs 16K/256K/1M/N) -------------------------------
__global__ void k_walk_lvl0(const int2* __restrict__ packed,
                            float* __restrict__ cum, int hi, int N) {
    int i = blockIdx.x * blockDim.x + threadIdx.x;
    if (i >= hi) return;
    float s = 0.0f; int j = i;
    while (j != N) { int2 pv = packed[j]; s += __int_as_float(pv.y); j = pv.x; }
    cum[i] = s;
}

__global__ void k_walk_lvl(const int2* __restrict__ packed,
                           float* __restrict__ cum, int lo, int hi, int cutoff) {
    int i = lo + blockIdx.x * blockDim.x + threadIdx.x;
    if (i >= hi) return;
    float s = 0.0f; int j = i;
    do { int2 pv = packed[j]; s += __int_as_float(pv.y); j = pv.x; } while (j >= cutoff);
    cum[i] = s + cum[j];
}

// ---------------- shared exclusive scan over NB bins (256 threads) ------------
__device__ __forceinline__ void exscan_bins(int* __restrict__ cnt,   // in: counts
                                            int* __restrict__ chEx,  // out: excl
                                            int* __restrict__ wsum) {
    int tid = threadIdx.x, lane = tid & 63, wave = tid >> 6;
    int b0 = 2*tid;
    int s0 = cnt[b0], s1 = cnt[b0+1], s = s0 + s1;
    int inc = s;
    #pragma unroll
    for (int d = 1; d < 64; d <<= 1) { int o = __shfl_up(inc, d); if (lane >= d) inc += o; }
    if (lane == 63) wsum[wave] = inc;
    __syncthreads();
    int wb = 0;
    for (int ww = 0; ww < wave; ++ww) wb += wsum[ww];
    int ex = wb + inc - s;
    chEx[b0] = ex; chEx[b0+1] = ex + s0;
}

// ---------------- scatter: LDS-atomic ranks, LDS-staged, parallel run-out -----
__global__ __launch_bounds__(256) void k_scatter512(
        const int* __restrict__ ptn, const unsigned short* __restrict__ wcnt,
        const int* __restrict__ bases, int* __restrict__ nv,
        unsigned short* __restrict__ slotLocal, int shift) {
    __shared__ int cnt[NB];
    __shared__ int chEx[NB];
    __shared__ int alloc[NB];
    __shared__ int sbase[NB];
    __shared__ int ldss[CHUNK_PX];
    __shared__ int wsum[4];
    int chunk = blockIdx.x;
    int tid = threadIdx.x;
    const unsigned short* wc = wcnt + (size_t)chunk * NB;
    const int* bs = bases + (size_t)chunk * NB;
    for (int i = tid; i < NB; i += 256) { cnt[i] = wc[i]; sbase[i] = bs[i]; }
    __syncthreads();
    exscan_bins(cnt, chEx, wsum);
    __syncthreads();
    for (int i = tid; i < NB; i += 256) alloc[i] = chEx[i];
    __syncthreads();
    // rank via LDS atomic; record node in ldss and 13-bit slot per pixel
    const v4i* p4 = reinterpret_cast<const v4i*>(ptn) + (size_t)chunk * CV4;
    unsigned long long* sl8 = reinterpret_cast<unsigned long long*>(slotLocal)
                              + (size_t)chunk * CV4;
    for (int t = 0; t < CV4/256; ++t) {
        v4i ia = __builtin_nontemporal_load(p4 + t*256 + tid);
        int s0 = atomicAdd(&alloc[ia.x >> shift], 1);
        int s1 = atomicAdd(&alloc[ia.y >> shift], 1);
        int s2 = atomicAdd(&alloc[ia.z >> shift], 1);
        int s3 = atomicAdd(&alloc[ia.w >> shift], 1);
        ldss[s0] = ia.x; ldss[s1] = ia.y; ldss[s2] = ia.z; ldss[s3] = ia.w;
        unsigned long long pk = (unsigned long long)(unsigned)s0
                              | ((unsigned long long)(unsigned)s1 << 16)
                              | ((unsigned long long)(unsigned)s2 << 32)
                              | ((unsigned long long)(unsigned)s3 << 48);
        sl8[t*256 + tid] = pk;
    }
    __syncthreads();
    // slot-parallel run write-out: bin derivable from the node itself
    for (int s = tid; s < CHUNK_PX; s += 256) {
        int node = ldss[s];
        int b = node >> shift;
        nv[sbase[b] + (s - chEx[b])] = node;
    }
}

// ---------------- gather: LDS-staged 32KB cum slice, in-place int->float ------
__global__ __launch_bounds__(512) void k_gather512(
        int* __restrict__ nv, const float* __restrict__ cum,
        const int* __restrict__ binStart, const int* __restrict__ binCnt,
        int shift, int N) {
    __shared__ float slice[8192];
    int b = blockIdx.x;
    int base = b << shift;
    int W = 1 << shift;
    for (int i = threadIdx.x; i < W; i += 512) {
        int idx = base + i;
        slice[i] = (idx < N) ? cum[idx] : 0.0f;
    }
    __syncthreads();
    int s = binStart[b], cnt = binCnt[b];
    int nq = cnt >> 2;
    v4i* np = reinterpret_cast<v4i*>(nv + s);      // 64-aligned starts
    v4f* vp = reinterpret_cast<v4f*>(nv + s);
    for (int q = threadIdx.x; q < nq; q += 512) {
        v4i na = __builtin_nontemporal_load(np + q);
        v4f va;
        va.x = slice[na.x - base];
        va.y = slice[na.y - base];
        va.z = slice[na.z - base];
        va.w = slice[na.w - base];
        vp[q] = va;                                 // in-place: same thread, same slot
    }
    int r = cnt & 3;
    if ((int)threadIdx.x < r) {
        int i = s + nq*4 + threadIdx.x;
        float v = slice[nv[i] - base];
        reinterpret_cast<float*>(nv)[i] = v;
    }
}

// ---------------- merge: stream runs into LDS (binary-searched), resolve ------
__global__ __launch_bounds__(256) void k_merge512(
        const unsigned short* __restrict__ wcnt, const int* __restrict__ bases,
        const float* __restrict__ nvf, const unsigned short* __restrict__ slotLocal,
        float* __restrict__ out) {
    __shared__ int cnt[NB];
    __shared__ int chEx[NB + 1];
    __shared__ int sbase[NB];
    __shared__ float ldsv[CHUNK_PX];
    __shared__ int wsum[4];
    int chunk = blockIdx.x;
    int tid = threadIdx.x;
    const unsigned short* wc = wcnt + (size_t)chunk * NB;
    const int* bs = bases + (size_t)chunk * NB;
    for (int i = tid; i < NB; i += 256) { cnt[i] = wc[i]; sbase[i] = bs[i]; }
    __syncthreads();
    exscan_bins(cnt, chEx, wsum);
    if (tid == 0) chEx[NB] = CHUNK_PX;
    __syncthreads();
    // copy this chunk's value runs into LDS, slot-parallel (coalesced reads)
    for (int s = tid; s < CHUNK_PX; s += 256) {
        int lo = 0, hi = NB;                 // find last b with chEx[b] <= s
        while (hi - lo > 1) { int mid = (lo + hi) >> 1;
                              if (chEx[mid] <= s) lo = mid; else hi = mid; }
        ldsv[s] = nvf[sbase[lo] + (s - chEx[lo])];
    }
    __syncthreads();
    const unsigned long long* sl8 = reinterpret_cast<const unsigned long long*>(slotLocal)
                                    + (size_t)chunk * CV4;
    v4f* o4 = reinterpret_cast<v4f*>(out) + (size_t)chunk * CV4;
    for (int t = 0; t < CV4/256; ++t) {
        unsigned long long pk = __builtin_nontemporal_load(sl8 + t*256 + tid);
        v4f o;
        o.x = ldsv[pk & 0xFFFF];
        o.y = ldsv[(pk >> 16) & 0xFFFF];
        o.z = ldsv[(pk >> 32) & 0xFFFF];
        o.w = ldsv[(pk >> 48) & 0xFFFF];
        o4[t*256 + tid] = o;                 // coalesced pixel-order write
    }
}

// ---------------- fallback: direct pixel gather -------------------------------
__global__ void k_pixel_gather(const float* __restrict__ cum,
                               const int* __restrict__ ptn,
                               float* __restrict__ out, int M) {
    int t = blockIdx.x * blockDim.x + threadIdx.x;
    int base = t * 4;
    if (base + 3 < M) {
        v4i idx = __builtin_nontemporal_load(reinterpret_cast<const v4i*>(ptn) + t);
        float4 o;
        o.x = cum[idx.x]; o.y = cum[idx.y]; o.z = cum[idx.z]; o.w = cum[idx.w];
        reinterpret_cast<float4*>(out)[t] = o;
    } else {
        for (int p = base; p < M; ++p) out[p] = cum[ptn[p]];
    }
}

extern "C" void kernel_launch(void* const* d_in, const int* in_sizes, int n_in,
                              void* d_out, int out_size, void* d_ws, size_t ws_size,
                              hipStream_t stream) {
    const float* attrs   = (const float*)d_in[0];
    const float* weight  = (const float*)d_in[1];
    const float* bias    = (const float*)d_in[2];
    const float* residue = (const float*)d_in[3];
    const int*   parent  = (const int*)d_in[4];
    const int*   ptn     = (const int*)d_in[5];
    float* out = (float*)d_out;

    const int N  = in_sizes[3];
    const int HW = in_sizes[5];
    const int BLK = 256;

    int shift = 0;
    while (((long)(N - 1) >> shift) >= NB) ++shift;
    int nBins = (int)(((long)(N - 1) >> shift) + 1);

    const int nChunks = HW / CHUNK_PX;
    const int nGroups = nChunks / 32;

    auto align256 = [](size_t x) { return (x + 255) & ~(size_t)255; };
    const size_t cumB   = align256((size_t)(N + 1) * 4);
    const size_t pkB    = (size_t)(N + 1) * 8;
    const size_t slB    = (size_t)HW * 2;
    const size_t regA   = align256(pkB > slB ? pkB : slB);     // packed / slotLocal alias
    const size_t nvB    = align256(((size_t)HW + (size_t)NB*64) * 4);
    const size_t wcntB  = align256((size_t)nChunks * NB * 2);
    const size_t PB     = align256((size_t)nGroups * NB * 4);
    const size_t basesB = align256((size_t)nChunks * NB * 4);
    const size_t need   = cumB + regA + nvB + wcntB + PB + basesB + 4096;

    float* cum    = (float*)d_ws;
    int2*  packed = (int2*)((char*)d_ws + cumB);
    unsigned short* slotLocal = (unsigned short*)((char*)d_ws + cumB);  // alias (packed dead)
    int*   nv     = (int*)((char*)d_ws + cumB + regA);
    unsigned short* wcnt = (unsigned short*)((char*)d_ws + cumB + regA + nvB);
    int*   P      = (int*)((char*)d_ws + cumB + regA + nvB + wcntB);
    int*   bases  = (int*)((char*)d_ws + cumB + regA + nvB + wcntB + PB);
    int*   binStart = (int*)((char*)d_ws + cumB + regA + nvB + wcntB + PB + basesB);
    int*   binCnt   = binStart + NB;

    bool binnedOK = (HW % CHUNK_PX == 0) && (nChunks % 32 == 0) && (nChunks >= 32) &&
                    (shift <= 13) && (ws_size >= need) && (N >= 2);

    // A) gate+pack | count512
    int g1 = (N + 1 + BLK - 1) / BLK;
    int gC = binnedOK ? nChunks : 0;
    k_gate_count512<<<g1 + gC, BLK, 0, stream>>>(attrs, weight, bias, residue,
                                                 parent, packed, N,
                                                 ptn, wcnt, shift, g1);

    if (binnedOK) {
        k_scanA<<<nGroups, 512, 0, stream>>>(wcnt, P);
        k_scanB<<<1, 512, 0, stream>>>(P, binStart, binCnt, nGroups);
        k_scanC<<<nGroups, 512, 0, stream>>>(wcnt, P, binStart, bases);
    }

    // walks: cutoffs 16K / 256K / 1M / N
    int c0 = 16384;   if (c0 > N) c0 = N;
    int c1 = 262144;  if (c1 > N) c1 = N;
    int c2 = 1048576; if (c2 > N) c2 = N;

    k_walk_lvl0<<<(c0 + BLK - 1) / BLK, BLK, 0, stream>>>(packed, cum, c0, N);
    if (c1 > c0)
        k_walk_lvl<<<(c1 - c0 + BLK - 1) / BLK, BLK, 0, stream>>>(packed, cum, c0, c1, c0);
    if (c2 > c1)
        k_walk_lvl<<<(c2 - c1 + BLK - 1) / BLK, BLK, 0, stream>>>(packed, cum, c1, c2, c1);
    if (N > c2)
        k_walk_lvl<<<(N - c2 + BLK - 1) / BLK, BLK, 0, stream>>>(packed, cum, c2, N, c2);

    if (binnedOK) {
        // packed is dead from here on; slotLocal reuses its region
        k_scatter512<<<nChunks, BLK, 0, stream>>>(ptn, wcnt, bases, nv, slotLocal, shift);
        k_gather512<<<nBins, 512, 0, stream>>>(nv, cum, binStart, binCnt, shift, N);
        k_merge512<<<nChunks, BLK, 0, stream>>>(wcnt, bases, (const float*)nv,
                                                slotLocal, out);
    } else {
        int nQuads = (HW + 3) / 4;
        k_pixel_gather<<<(nQuads + BLK - 1) / BLK, BLK, 0, stream>>>(cum, ptn, out, HW);
    }
}